// Round 8
// baseline (1765.434 us; speedup 1.0000x reference)
//
#include <hip/hip_runtime.h>
#include <stdint.h>

// ============================ problem constants ============================
constexpr int VOC  = 50257;
constexpr int VPAD = 50304;          // VOC padded to multiple of 128
constexpr int DEMB = 768;
constexpr int NQ   = 4096;           // B*T
constexpr float EPS_HALF = 0.05f;    // EPSILON / 2
constexpr float LOG2E = 1.4426950408889634f;
constexpr float C16   = -23.083120654223414f;   // -16*log2(e); fixed softmax "max"
// logit = sim*0.05 + gumbel < 16 always; P = exp2(simraw*rk2 + C16) / (-ln u)

typedef __attribute__((ext_vector_type(4))) short    short4_t;
typedef __attribute__((ext_vector_type(8))) short    short8_t;
typedef __attribute__((ext_vector_type(4))) float    float4_t;
typedef __attribute__((ext_vector_type(4))) uint32_t uint4_t;

// ============================ small helpers ================================
__device__ __forceinline__ short f2bf(float f) {   // RNE float->bf16
  uint32_t u = __float_as_uint(f);
  u += 0x7FFFu + ((u >> 16) & 1u);
  return (short)(u >> 16);
}

// ---- 8 independent threefry2x32 hashes, key (0,42), counters e0..e0+7 ----
__device__ __forceinline__ void tf8(uint32_t e0, uint32_t out[8]) {
  const uint32_t K0 = 0u, K1 = 42u, K2 = 0x1BD11BDAu ^ 42u;
  uint32_t x0[8], x1[8];
#pragma unroll
  for (int r = 0; r < 8; ++r) { x0[r] = K0; x1[r] = e0 + (uint32_t)r + K1; }
#define R8(a) _Pragma("unroll") \
  for (int r = 0; r < 8; ++r) { x0[r] += x1[r]; x1[r] = __builtin_rotateleft32(x1[r], a) ^ x0[r]; }
#define INJ8(a, b, i) _Pragma("unroll") \
  for (int r = 0; r < 8; ++r) { x0[r] += (a); x1[r] += (b) + (uint32_t)(i); }
  R8(13) R8(15) R8(26) R8(6)
  INJ8(K1, K2, 1)
  R8(17) R8(29) R8(16) R8(24)
  INJ8(K2, K0, 2)
  R8(13) R8(15) R8(26) R8(6)
  INJ8(K0, K1, 3)
  R8(17) R8(29) R8(16) R8(24)
  INJ8(K1, K2, 4)
  R8(13) R8(15) R8(26) R8(6)
#pragma unroll
  for (int r = 0; r < 8; ++r) { x0[r] += K2; x1[r] += K0 + 5u; out[r] = x0[r] ^ x1[r]; }
#undef R8
#undef INJ8
}

// t = -ln(u), u = n*2^-23. Branchless; series near u->1 avoids log cancellation.
__device__ __forceinline__ float neg_ln_u(uint32_t bits) {
  uint32_t n = bits >> 9;
  uint32_t m = 8388608u - n;
  float t_log = (23.0f - __builtin_amdgcn_logf((float)n)) * 0.69314718055994531f;
  float x = (float)m * 1.1920928955078125e-7f;
  float t_ser = x * fmaf(x, fmaf(x, fmaf(x, 0.25f, 0.3333333333f), 0.5f), 1.0f);
  return (m < 32768u) ? t_ser : t_log;
}

// ===================== fragment-tile layouts ===============================
// P/S: off(qb, ktile, q, kin) = ((qb*(KC/32)+ktile)*128 + q)*32 + kin  [shorts]
//      (8KB tile; gemm2 A-frag read = row*64B + kgroup*16B: bijective, coalesced)
// Et : off(ktG, db, d, kin)   = ((ktG*6+db)*128 + d)*32 + kin          [shorts]

// ============================ prep kernels =================================
__global__ void k_prep_e(const float* __restrict__ E, short* __restrict__ Eb,
                         float* __restrict__ rk2) {
  int j = blockIdx.x;            // 0..VPAD-1
  int t = threadIdx.x;
  __shared__ float red[4];
  float ssq = 0.f;
  if (j < VOC) {
    if (t < 192) {
      float4_t v = *(const float4_t*)(E + (size_t)j * DEMB + t * 4);
      ssq = v[0]*v[0] + v[1]*v[1] + v[2]*v[2] + v[3]*v[3];
      short4_t b; b[0]=f2bf(v[0]); b[1]=f2bf(v[1]); b[2]=f2bf(v[2]); b[3]=f2bf(v[3]);
      *(short4_t*)(Eb + (size_t)j * DEMB + t * 4) = b;
    }
  } else if (t < 192) {
    short4_t z = {0,0,0,0};
    *(short4_t*)(Eb + (size_t)j * DEMB + t * 4) = z;
  }
  for (int off = 32; off; off >>= 1) ssq += __shfl_xor(ssq, off);
  if ((t & 63) == 0) red[t >> 6] = ssq;
  __syncthreads();
  if (t == 0) {
    float s = red[0] + red[1] + red[2] + red[3];
    rk2[j] = (j < VOC) ? (EPS_HALF * LOG2E / fmaxf(sqrtf(s), 1e-12f)) : 0.f;
  }
}

__global__ void k_prep_q(const int* __restrict__ ids, const float* __restrict__ E,
                         short* __restrict__ qn) {
  int p = blockIdx.x;
  int t = threadIdx.x;
  int id = ids[p];
  __shared__ float red[4];
  __shared__ float scale_s;
  float4_t v = {0.f, 0.f, 0.f, 0.f};
  float ssq = 0.f;
  if (t < 192) {
    v = *(const float4_t*)(E + (size_t)id * DEMB + t * 4);
    ssq = v[0]*v[0] + v[1]*v[1] + v[2]*v[2] + v[3]*v[3];
  }
  for (int off = 32; off; off >>= 1) ssq += __shfl_xor(ssq, off);
  if ((t & 63) == 0) red[t >> 6] = ssq;
  __syncthreads();
  if (t == 0) scale_s = 1.0f / fmaxf(sqrtf(red[0]+red[1]+red[2]+red[3]), 1e-12f);
  __syncthreads();
  float sc = scale_s;
  if (t < 192) {
    short4_t b; b[0]=f2bf(v[0]*sc); b[1]=f2bf(v[1]*sc); b[2]=f2bf(v[2]*sc); b[3]=f2bf(v[3]*sc);
    *(short4_t*)(qn + (size_t)p * DEMB + t * 4) = b;
  }
}

// Eb[key][d] -> Et fragment tiles
__global__ void k_transpose(const short* __restrict__ Eb, short* __restrict__ Et) {
  int lane = threadIdx.x & 63;
  int dg   = threadIdx.x >> 6;
  int key  = blockIdx.x * 64 + lane;
  int d0   = blockIdx.y * 32 + dg * 8;
  short8_t v = *(const short8_t*)(Eb + (size_t)key * DEMB + d0);
  short* dst = Et + ((size_t)(key >> 5) * 6 + (d0 >> 7)) * 4096 + (d0 & 127) * 32 + (key & 31);
#pragma unroll
  for (int q = 0; q < 8; ++q) dst[q * 32] = v[q];
}

__global__ void k_zero(float* __restrict__ O, float* __restrict__ lsum) {
  int idx = blockIdx.x * 256 + threadIdx.x;      // float4 index over O
  if (idx < NQ) lsum[idx] = 0.f;
  float4_t z = {0.f, 0.f, 0.f, 0.f};
  ((float4_t*)O)[idx] = z;
}

// =================== gemm1 LDS plumbing (BK=64, proven R6 form) ============
__device__ __forceinline__ int swz(int row, int byte) {
  return (row << 7) + (byte ^ ((row & 7) << 4));
}
__device__ __forceinline__ void stage_g2l(short* L, const short* __restrict__ g,
                                          long grow0, long stride, long col0, int tid) {
  int r7 = tid >> 3;
  int c8 = (tid & 7) << 3;
#pragma unroll
  for (int i = 0; i < 4; ++i) {
    int  row = r7 + i * 32;
    long cs  = (long)(c8 ^ ((row & 7) << 3));
    const short* src = g + (grow0 + row) * stride + col0 + cs;
    short* dst = L + row * 64 + c8;
    __builtin_amdgcn_global_load_lds(
        (const __attribute__((address_space(1))) void*)src,
        (__attribute__((address_space(3))) void*)dst, 16, 0, 0);
  }
}
__device__ __forceinline__ short8_t ldfrag(const short* L, int row, int kbyte) {
  return *(const short8_t*)(L + (swz(row, kbyte) >> 1));
}

// ============================== roles ======================================
// role 1: S[qb, ktile, q, kin] = qn_q . Eb_j  (raw sim, f16, frag-tiled)
__device__ __forceinline__ void role_gemm1(
    const short* __restrict__ qn, const short* __restrict__ Eb,
    _Float16* __restrict__ S, int c0, int KC, int i1, short* lA, short* lB) {
  int tid = threadIdx.x, lane = tid & 63;
  int wv = tid >> 6, wr = wv >> 1, wc = wv & 1;
  int bx = i1 & 31;                 // query block (32)
  int by = i1 >> 5;                 // col block within chunk
  int rowbase = bx * 128;
  int colbase = by * 128;
  float4_t acc[4][4];
  float4_t zero = {0.f, 0.f, 0.f, 0.f};
#pragma unroll
  for (int mt = 0; mt < 4; ++mt)
#pragma unroll
    for (int nt = 0; nt < 4; ++nt) acc[mt][nt] = zero;

  for (int kt = 0; kt < DEMB / 64; ++kt) {
    __syncthreads();
    stage_g2l(lA, qn, rowbase,      DEMB, kt * 64, tid);
    stage_g2l(lB, Eb, c0 + colbase, DEMB, kt * 64, tid);
    __syncthreads();
#pragma unroll
    for (int ks = 0; ks < 2; ++ks) {
      int kb = ks * 64 + (lane >> 4) * 16;
      short8_t a[4], b[4];
#pragma unroll
      for (int mt = 0; mt < 4; ++mt) a[mt] = ldfrag(lA, wr * 64 + mt * 16 + (lane & 15), kb);
#pragma unroll
      for (int nt = 0; nt < 4; ++nt) b[nt] = ldfrag(lB, wc * 64 + nt * 16 + (lane & 15), kb);
#pragma unroll
      for (int mt = 0; mt < 4; ++mt)
#pragma unroll
        for (int nt = 0; nt < 4; ++nt)
          acc[mt][nt] = __builtin_amdgcn_mfma_f32_16x16x32_bf16(a[mt], b[nt], acc[mt][nt], 0, 0, 0);
    }
  }
  // epilogue -> frag-tiled S  (C/D: col = lane&15, row = (lane>>4)*4 + reg)
#pragma unroll
  for (int mt = 0; mt < 4; ++mt) {
    int q0 = wr * 64 + mt * 16 + ((lane >> 4) << 2);
#pragma unroll
    for (int nt = 0; nt < 4; ++nt) {
      int ktile = (colbase + wc * 64 + nt * 16) >> 5;
      int kin   = ((nt & 1) << 4) + (lane & 15);
      _Float16* dst = S + ((size_t)bx * (KC >> 5) + ktile) * 4096 + kin;
#pragma unroll
      for (int r = 0; r < 4; ++r) dst[(q0 + r) * 32] = (_Float16)acc[mt][nt][r];
    }
  }
}

// role 2: in-place f16 sim -> bf16 P (frag-tiled), + row-sum atomics
__device__ __forceinline__ void role_gumbel(
    uint32_t* __restrict__ SP, const float* __restrict__ rk2,
    float* __restrict__ lsum, int c0, int KCeff, int KC, int i2) {
  int p  = i2 & (NQ - 1);
  int ky = i2 >> 12;
  int t  = threadIdx.x;
  int colq = ky * 2048 + t * 8;
  float partial = 0.f;
  if (colq < KCeff) {
    int qb = p >> 7, q = p & 127;
    size_t off = ((size_t)qb * (KC >> 5) + (colq >> 5)) * 4096 + q * 32 + (colq & 31);
    uint32_t* base = SP + (off >> 1);
    uint4_t sv = *(const uint4_t*)base;                    // 8 f16 sims
    int j0 = c0 + colq;
    float4_t rk_lo = *(const float4_t*)(rk2 + j0);
    float4_t rk_hi = *(const float4_t*)(rk2 + j0 + 4);
    uint32_t bits[8];
    tf8((uint32_t)p * (uint32_t)VOC + (uint32_t)j0, bits);
    float pe[8];
#pragma unroll
    for (int i = 0; i < 8; ++i) {
      uint32_t h = (sv[i >> 1] >> ((i & 1) * 16)) & 0xFFFFu;
      _Float16 hf = *(_Float16*)&h;
      float simf = (float)hf;
      float rkj = (i < 4) ? rk_lo[i] : rk_hi[i - 4];
      float tt = neg_ln_u(bits[i]);
      float v = __builtin_amdgcn_exp2f(fmaf(simf, rkj, C16)) * __builtin_amdgcn_rcpf(tt);
      bool ok = (j0 + i) < VOC;
      pe[i] = ok ? v : 0.f;
      partial += pe[i];
    }
    uint4_t pkv;
#pragma unroll
    for (int i = 0; i < 4; ++i) {
      uint32_t r;
      asm("v_cvt_pk_bf16_f32 %0, %1, %2" : "=v"(r) : "v"(pe[2 * i]), "v"(pe[2 * i + 1]));
      pkv[i] = r;
    }
    *(uint4_t*)base = pkv;
  }
  for (int off = 32; off; off >>= 1) partial += __shfl_xor(partial, off);
  if ((t & 63) == 0 && partial != 0.f) unsafeAtomicAdd(&lsum[p], partial);
}

// role 3: O[p][d] += sum_k P[p][k]*E[k][d] — LDS-free, barrier-free frag GEMM
__device__ __forceinline__ void role_gemm2(
    const short* __restrict__ P, const short* __restrict__ Et,
    float* __restrict__ O, int c0, int KC, int kseg, int i3) {
  int tid = threadIdx.x, lane = tid & 63;
  int wv = tid >> 6, wr = wv >> 1, wc = wv & 1;
  int qb = i3 & 31;
  int db = (i3 >> 5) % 6;
  int zs = i3 / 192;
  int kt0 = (zs * kseg) >> 5;
  int nk  = kseg >> 5;
  float4_t acc[4][4];
  float4_t zero = {0.f, 0.f, 0.f, 0.f};
#pragma unroll
  for (int mt = 0; mt < 4; ++mt)
#pragma unroll
    for (int nt = 0; nt < 4; ++nt) acc[mt][nt] = zero;

  const short* Ab = P + (size_t)qb * (KC >> 5) * 4096;
  int aoff = (wr * 64 + (lane & 15)) * 32 + ((lane >> 4) << 3);
  int boff = (wc * 64 + (lane & 15)) * 32 + ((lane >> 4) << 3);
#pragma unroll 2
  for (int kt = 0; kt < nk; ++kt) {
    const short* At = Ab + (size_t)(kt0 + kt) * 4096;
    const short* Bt = Et + ((size_t)((c0 >> 5) + kt0 + kt) * 6 + db) * 4096;
    short8_t a[4], b[4];
#pragma unroll
    for (int mt = 0; mt < 4; ++mt) a[mt] = *(const short8_t*)(At + aoff + mt * 512);
#pragma unroll
    for (int nt = 0; nt < 4; ++nt) b[nt] = *(const short8_t*)(Bt + boff + nt * 512);
#pragma unroll
    for (int mt = 0; mt < 4; ++mt)
#pragma unroll
      for (int nt = 0; nt < 4; ++nt)
        acc[mt][nt] = __builtin_amdgcn_mfma_f32_16x16x32_bf16(a[mt], b[nt], acc[mt][nt], 0, 0, 0);
  }
#pragma unroll
  for (int mt = 0; mt < 4; ++mt)
#pragma unroll
    for (int nt = 0; nt < 4; ++nt) {
      int d = db * 128 + wc * 64 + nt * 16 + (lane & 15);
#pragma unroll
      for (int r = 0; r < 4; ++r) {
        int p = qb * 128 + wr * 64 + mt * 16 + ((lane >> 4) << 2) + r;
        unsafeAtomicAdd(&O[(size_t)p * DEMB + d], acc[mt][nt][r]);
      }
    }
}

// ============================ uber kernel ==================================
// One launch runs three independent roles concurrently (software pipeline over
// chunks): gemm1(chunk t) || gumbel(t-1) || gemm2(t-2).  Exact two-level
// Bresenham interleaves block types across dispatch order so every CU gets a
// mix of MFMA-heavy, VALU-heavy and load-heavy blocks.
__global__ __launch_bounds__(256) void k_uber(
    const short* __restrict__ qn, const short* __restrict__ Eb,
    const float* __restrict__ rk2, const short* __restrict__ Et,
    float* __restrict__ O, float* __restrict__ lsum,
    _Float16* __restrict__ S1, uint32_t* __restrict__ SPg,
    const short* __restrict__ P2,
    int n1, int n2, int n3,
    int c0a, int c0g, int kcg, int c0b, int kseg, int KC) {
  __shared__ short lA[128 * 64];
  __shared__ short lB[128 * 64];
  long b = blockIdx.x;
  long N = (long)n1 + n2 + n3;
  long c1 = ((b + 1) * (long)n1) / N;
  if (c1 - (b * (long)n1) / N) {
    role_gemm1(qn, Eb, S1, c0a, KC, (int)(c1 - 1), lA, lB);
    return;
  }
  long r = b - c1;
  long M = (long)n2 + n3;
  long c2 = ((r + 1) * (long)n2) / M;
  if (c2 - (r * (long)n2) / M) {
    role_gumbel(SPg, rk2, lsum, c0g, kcg, KC, (int)(c2 - 1));
    return;
  }
  role_gemm2(P2, Et, O, c0b, KC, kseg, (int)(r - c2));
}

__global__ void k_finalize(const float* __restrict__ O, const float* __restrict__ lsum,
                           float* __restrict__ out) {
  int idx = blockIdx.x * 256 + threadIdx.x;      // float4 index
  float inv = 1.0f / lsum[idx / 192];            // 192 float4 per row
  float4_t v = ((const float4_t*)O)[idx];
  v[0]*=inv; v[1]*=inv; v[2]*=inv; v[3]*=inv;
  ((float4_t*)out)[idx] = v;
}

// ============================ host launcher ================================
extern "C" void kernel_launch(void* const* d_in, const int* in_sizes, int n_in,
                              void* d_out, int out_size, void* d_ws, size_t ws_size,
                              hipStream_t stream) {
  (void)in_sizes; (void)n_in; (void)out_size;
  const int*   ids = (const int*)d_in[0];
  const float* E   = (const float*)d_in[1];
  float*       out = (float*)d_out;

  char* w = (char*)d_ws;
  short* Eb = (short*)w;      w += (size_t)VPAD * DEMB * 2;   // 77.3 MB
  short* Et = (short*)w;      w += (size_t)(VPAD / 32) * 6 * 4096 * 2;  // 77.3 MB
  short* qn = (short*)w;      w += (size_t)NQ * DEMB * 2;     // 6.3 MB
  float* O  = (float*)w;      w += (size_t)NQ * DEMB * 4;     // 12.6 MB
  float* rk2 = (float*)w;     w += (size_t)VPAD * 4;
  float* lsum = (float*)w;    w += NQ * 4;
  short* ring = (short*)w;                                    // 3 x S/P chunk
  size_t fixed = (size_t)(w - (char*)d_ws);

  int KC = 2048;                                              // 3-ring must fit
  if      (fixed + 3 * (size_t)NQ * 8192 * 2 <= ws_size) KC = 8192;
  else if (fixed + 3 * (size_t)NQ * 4096 * 2 <= ws_size) KC = 4096;
  size_t ringElems = (size_t)NQ * KC;                         // shorts per ring slot
  int chunks = (VPAD + KC - 1) / KC;
  auto kceff = [&](int c) { int k = VPAD - c * KC; return k > KC ? KC : k; };

  k_zero<<<(NQ * DEMB / 4) / 256, 256, 0, stream>>>(O, lsum);
  k_prep_e<<<VPAD, 256, 0, stream>>>(E, Eb, rk2);
  k_prep_q<<<NQ, 256, 0, stream>>>(ids, E, qn);
  k_transpose<<<dim3(VPAD / 64, DEMB / 32), 256, 0, stream>>>(Eb, Et);

  for (int s = 0; s <= chunks + 1; ++s) {
    int n1 = 0, n2 = 0, n3 = 0;
    int c0a = 0, c0g = 0, kcg = 0, c0b = 0, kseg = 0;
    if (s < chunks)              { c0a = s * KC;       n1 = 32 * (kceff(s) >> 7); }
    if (s >= 1 && s <= chunks)   { c0g = (s - 1) * KC; kcg = kceff(s - 1);
                                   n2 = NQ * ((kcg + 2047) / 2048); }
    if (s >= 2)                  { c0b = (s - 2) * KC; kseg = kceff(s - 2) / 4;
                                   n3 = 32 * 6 * 4; }
    int grid = n1 + n2 + n3;
    if (!grid) continue;
    _Float16* S1  = (_Float16*)(ring + (size_t)(s % 3) * ringElems);
    uint32_t* SPg = (uint32_t*)(ring + (size_t)((s + 2) % 3) * ringElems);  // (s-1)%3
    const short* P2 = ring + (size_t)((s + 1) % 3) * ringElems;             // (s-2)%3
    k_uber<<<grid, 256, 0, stream>>>(qn, Eb, rk2, Et, O, lsum,
                                     S1, SPg, P2, n1, n2, n3,
                                     c0a, c0g, kcg, c0b, kseg, KC);
  }
  k_finalize<<<(NQ * DEMB / 4) / 256, 256, 0, stream>>>(O, lsum, out);
}

// Round 9
// 1519.259 us; speedup vs baseline: 1.1620x; 1.1620x over previous
//
#include <hip/hip_runtime.h>
#include <stdint.h>

// ============================ problem constants ============================
constexpr int VOC  = 50257;
constexpr int VPAD = 50304;          // VOC padded to multiple of 128
constexpr int DEMB = 768;
constexpr int NQ   = 4096;           // B*T
constexpr float EPS_HALF = 0.05f;    // EPSILON / 2
constexpr float LOG2E = 1.4426950408889634f;
constexpr float C16   = -23.083120654223414f;   // -16*log2(e); fixed softmax "max"
// logit = sim*0.05 + gumbel < 16 always; P = exp2(simraw*rk2 + C16) / (-ln u)

typedef __attribute__((ext_vector_type(4))) short    short4_t;
typedef __attribute__((ext_vector_type(8))) short    short8_t;
typedef __attribute__((ext_vector_type(4))) float    float4_t;
typedef __attribute__((ext_vector_type(4))) uint32_t uint4_t;

// ============================ small helpers ================================
__device__ __forceinline__ short f2bf(float f) {   // RNE float->bf16
  uint32_t u = __float_as_uint(f);
  u += 0x7FFFu + ((u >> 16) & 1u);
  return (short)(u >> 16);
}

// ---- 8 independent threefry2x32 hashes, key (0,42), counters e0..e0+7 ----
// bits = o0 ^ o1 (jax threefry_partitionable). Lockstep arrays -> 8-way ILP.
__device__ __forceinline__ void tf8(uint32_t e0, uint32_t out[8]) {
  const uint32_t K0 = 0u, K1 = 42u, K2 = 0x1BD11BDAu ^ 42u;
  uint32_t x0[8], x1[8];
#pragma unroll
  for (int r = 0; r < 8; ++r) { x0[r] = K0; x1[r] = e0 + (uint32_t)r + K1; }
#define R8(a) _Pragma("unroll") \
  for (int r = 0; r < 8; ++r) { x0[r] += x1[r]; x1[r] = __builtin_rotateleft32(x1[r], a) ^ x0[r]; }
#define INJ8(a, b, i) _Pragma("unroll") \
  for (int r = 0; r < 8; ++r) { x0[r] += (a); x1[r] += (b) + (uint32_t)(i); }
  R8(13) R8(15) R8(26) R8(6)
  INJ8(K1, K2, 1)
  R8(17) R8(29) R8(16) R8(24)
  INJ8(K2, K0, 2)
  R8(13) R8(15) R8(26) R8(6)
  INJ8(K0, K1, 3)
  R8(17) R8(29) R8(16) R8(24)
  INJ8(K1, K2, 4)
  R8(13) R8(15) R8(26) R8(6)
#pragma unroll
  for (int r = 0; r < 8; ++r) { x0[r] += K2; x1[r] += K0 + 5u; out[r] = x0[r] ^ x1[r]; }
#undef R8
#undef INJ8
}

// t = -ln(u), u = n*2^-23. Branchless; series near u->1 avoids log cancellation.
__device__ __forceinline__ float neg_ln_u(uint32_t bits) {
  uint32_t n = bits >> 9;
  uint32_t m = 8388608u - n;
  float t_log = (23.0f - __builtin_amdgcn_logf((float)n)) * 0.69314718055994531f;
  float x = (float)m * 1.1920928955078125e-7f;
  float t_ser = x * fmaf(x, fmaf(x, fmaf(x, 0.25f, 0.3333333333f), 0.5f), 1.0f);
  return (m < 32768u) ? t_ser : t_log;
}

// ============================ prep kernels =================================
// rk2[j] = (0.05/max(||E_j||,1e-12)) * log2e ; E -> bf16
__global__ void k_prep_e(const float* __restrict__ E, short* __restrict__ Eb,
                         float* __restrict__ rk2) {
  int j = blockIdx.x;            // 0..VPAD-1
  int t = threadIdx.x;
  __shared__ float red[4];
  float ssq = 0.f;
  if (j < VOC) {
    if (t < 192) {
      float4_t v = *(const float4_t*)(E + (size_t)j * DEMB + t * 4);
      ssq = v[0]*v[0] + v[1]*v[1] + v[2]*v[2] + v[3]*v[3];
      short4_t b; b[0]=f2bf(v[0]); b[1]=f2bf(v[1]); b[2]=f2bf(v[2]); b[3]=f2bf(v[3]);
      *(short4_t*)(Eb + (size_t)j * DEMB + t * 4) = b;
    }
  } else if (t < 192) {
    short4_t z = {0,0,0,0};
    *(short4_t*)(Eb + (size_t)j * DEMB + t * 4) = z;
  }
  for (int off = 32; off; off >>= 1) ssq += __shfl_xor(ssq, off);
  if ((t & 63) == 0) red[t >> 6] = ssq;
  __syncthreads();
  if (t == 0) {
    float s = red[0] + red[1] + red[2] + red[3];
    rk2[j] = (j < VOC) ? (EPS_HALF * LOG2E / fmaxf(sqrtf(s), 1e-12f)) : 0.f;
  }
}

__global__ void k_prep_q(const int* __restrict__ ids, const float* __restrict__ E,
                         short* __restrict__ qn) {
  int p = blockIdx.x;
  int t = threadIdx.x;
  int id = ids[p];
  __shared__ float red[4];
  __shared__ float scale_s;
  float4_t v = {0.f, 0.f, 0.f, 0.f};
  float ssq = 0.f;
  if (t < 192) {
    v = *(const float4_t*)(E + (size_t)id * DEMB + t * 4);
    ssq = v[0]*v[0] + v[1]*v[1] + v[2]*v[2] + v[3]*v[3];
  }
  for (int off = 32; off; off >>= 1) ssq += __shfl_xor(ssq, off);
  if ((t & 63) == 0) red[t >> 6] = ssq;
  __syncthreads();
  if (t == 0) scale_s = 1.0f / fmaxf(sqrtf(red[0]+red[1]+red[2]+red[3]), 1e-12f);
  __syncthreads();
  float sc = scale_s;
  if (t < 192) {
    short4_t b; b[0]=f2bf(v[0]*sc); b[1]=f2bf(v[1]*sc); b[2]=f2bf(v[2]*sc); b[3]=f2bf(v[3]*sc);
    *(short4_t*)(qn + (size_t)p * DEMB + t * 4) = b;
  }
}

// Et[d][key] = Eb[key][d]   (row-major, stride VPAD)
__global__ void k_transpose(const short* __restrict__ Eb, short* __restrict__ Et) {
  int lane = threadIdx.x & 63;
  int dg   = threadIdx.x >> 6;
  int key  = blockIdx.x * 64 + lane;
  int d0   = blockIdx.y * 32 + dg * 8;
  short8_t v = *(const short8_t*)(Eb + (size_t)key * DEMB + d0);
#pragma unroll
  for (int q = 0; q < 8; ++q)
    Et[(size_t)(d0 + q) * VPAD + key] = v[q];
}

__global__ void k_zero(float* __restrict__ O, float* __restrict__ lsum) {
  int idx = blockIdx.x * 256 + threadIdx.x;      // float4 index over O
  if (idx < NQ) lsum[idx] = 0.f;
  float4_t z = {0.f, 0.f, 0.f, 0.f};
  ((float4_t*)O)[idx] = z;
}

// ============================ GEMM plumbing ================================
// 128x128 tile, BK=64, 256 threads (4 waves, 2x2 quadrants of 64x64),
// 16x16x32 bf16 MFMA. LDS image: LDS[row][s] = g[row][s ^ ((row&7)<<3)] (shorts).
__device__ __forceinline__ int swz(int row, int byte) {
  return (row << 7) + (byte ^ ((row & 7) << 4));
}

// VGPR staging (global->VGPR->swizzled ds_write). The loads target private
// VGPRs, so the compiler may hoist NEXT-tile loads above the barrier and the
// current tile's MFMA phase -> deep natural prefetch (T14 mechanism; this is
// the R2 structure whose gemm2 ran ~2x faster than global_load_lds staging).
__device__ __forceinline__ void stage_vgpr(short* L, const short* __restrict__ g,
                                           int row0, int rowcap, long rowstride,
                                           long col0, int tid) {
  int row = tid >> 1;
  int ch  = (tid & 1) * 64;                      // byte half of the 128B row
  long grow = row0 + row; if (grow > rowcap) grow = rowcap;
  const short8_t* src = (const short8_t*)(g + grow * rowstride + col0 + (ch >> 1));
#pragma unroll
  for (int i = 0; i < 4; ++i) {
    short8_t v = src[i];
    *(short8_t*)(L + (swz(row, ch + i * 16) >> 1)) = v;
  }
}

// global_load_lds staging (linear LDS dest, pre-swizzled source) - same LDS
// image as stage_vgpr. Used for gemm1 whose operands are L2/L3-hot.
__device__ __forceinline__ void stage_g2l(short* L, const short* __restrict__ g,
                                          long grow0, long stride, long col0, int tid) {
  int r7 = tid >> 3;
  int c8 = (tid & 7) << 3;                       // short offset, 16B units
#pragma unroll
  for (int i = 0; i < 4; ++i) {
    int  row = r7 + i * 32;
    long cs  = (long)(c8 ^ ((row & 7) << 3));    // pre-swizzled source col (shorts)
    const short* src = g + (grow0 + row) * stride + col0 + cs;
    short* dst = L + row * 64 + c8;              // linear: lane-monotone 16B/lane
    __builtin_amdgcn_global_load_lds(
        (const __attribute__((address_space(1))) void*)src,
        (__attribute__((address_space(3))) void*)dst, 16, 0, 0);
  }
}

// single ds_read_b128 fragment; A and B use the identical within-K mapping so
// the permutation cancels inside the MFMA dot product.
__device__ __forceinline__ short8_t ldfrag(const short* L, int row, int kbyte) {
  return *(const short8_t*)(L + (swz(row, kbyte) >> 1));
}

// ---- GEMM1 (pure): S[p][jc] = qn_p . Eb_j   (raw sim, f16, row-major) ----
__global__ __launch_bounds__(256) void k_gemm1(
    const short* __restrict__ qn, const short* __restrict__ Eb,
    _Float16* __restrict__ S, int c0, int KC) {
  __shared__ short lA[128 * 64];
  __shared__ short lB[128 * 64];
  int tid = threadIdx.x, lane = tid & 63;
  int wv = tid >> 6, wr = wv >> 1, wc = wv & 1;
  int rowbase = blockIdx.x * 128;
  int colbase = blockIdx.y * 128;
  float4_t acc[4][4];
  float4_t zero = {0.f, 0.f, 0.f, 0.f};
#pragma unroll
  for (int mt = 0; mt < 4; ++mt)
#pragma unroll
    for (int nt = 0; nt < 4; ++nt) acc[mt][nt] = zero;

  for (int kt = 0; kt < DEMB / 64; ++kt) {
    __syncthreads();
    stage_g2l(lA, qn, rowbase,      DEMB, kt * 64, tid);
    stage_g2l(lB, Eb, c0 + colbase, DEMB, kt * 64, tid);
    __syncthreads();
#pragma unroll
    for (int ks = 0; ks < 2; ++ks) {
      int kb = ks * 64 + (lane >> 4) * 16;
      short8_t a[4], b[4];
#pragma unroll
      for (int mt = 0; mt < 4; ++mt) a[mt] = ldfrag(lA, wr * 64 + mt * 16 + (lane & 15), kb);
#pragma unroll
      for (int nt = 0; nt < 4; ++nt) b[nt] = ldfrag(lB, wc * 64 + nt * 16 + (lane & 15), kb);
#pragma unroll
      for (int mt = 0; mt < 4; ++mt)
#pragma unroll
        for (int nt = 0; nt < 4; ++nt)
          acc[mt][nt] = __builtin_amdgcn_mfma_f32_16x16x32_bf16(a[mt], b[nt], acc[mt][nt], 0, 0, 0);
    }
  }
  // epilogue: raw sims -> f16 (C/D layout: col = lane&15, row = (lane>>4)*4 + reg)
#pragma unroll
  for (int mt = 0; mt < 4; ++mt) {
    int prow = rowbase + wr * 64 + mt * 16 + ((lane >> 4) << 2);
    int jc0  = colbase + wc * 64 + (lane & 15);
#pragma unroll
    for (int r = 0; r < 4; ++r) {
      _Float16* dst = S + (size_t)(prow + r) * KC + jc0;
#pragma unroll
      for (int nt = 0; nt < 4; ++nt) dst[nt * 16] = (_Float16)acc[mt][nt][r];
    }
  }
}

// ---- gumbel/softmax pass: in-place f16 sim -> bf16 P, + row-sum atomics ----
// P = exp2(sim*rk2[j] + C16) * rcp(-ln u_j).  8 contiguous cols per thread.
__global__ __launch_bounds__(256) void k_gumbel(
    uint32_t* __restrict__ SP, const float* __restrict__ rk2,
    float* __restrict__ lsum, int c0, int KCeff, int KC) {
  int p    = blockIdx.x;
  int colq = blockIdx.y * 2048 + threadIdx.x * 8;
  float partial = 0.f;
  if (colq < KCeff) {
    uint32_t* base = SP + ((size_t)p * KC + colq) / 2;     // 2B elems -> u32 pairs
    uint4_t sv = *(const uint4_t*)base;                    // 8 f16 sims
    int j0 = c0 + colq;                                    // global vocab col
    float4_t rk_lo = *(const float4_t*)(rk2 + j0);
    float4_t rk_hi = *(const float4_t*)(rk2 + j0 + 4);
    uint32_t bits[8];
    tf8((uint32_t)p * (uint32_t)VOC + (uint32_t)j0, bits);
    float pe[8];
#pragma unroll
    for (int i = 0; i < 8; ++i) {
      uint32_t h = (sv[i >> 1] >> ((i & 1) * 16)) & 0xFFFFu;
      _Float16 hf = *(_Float16*)&h;
      float simf = (float)hf;
      float rkj = (i < 4) ? rk_lo[i] : rk_hi[i - 4];
      float t = neg_ln_u(bits[i]);
      float v = __builtin_amdgcn_exp2f(fmaf(simf, rkj, C16)) * __builtin_amdgcn_rcpf(t);
      bool ok = (j0 + i) < VOC;
      pe[i] = ok ? v : 0.f;
      partial += pe[i];
    }
    uint4_t pkv;
#pragma unroll
    for (int i = 0; i < 4; ++i) {
      uint32_t r;
      asm("v_cvt_pk_bf16_f32 %0, %1, %2" : "=v"(r) : "v"(pe[2 * i]), "v"(pe[2 * i + 1]));
      pkv[i] = r;
    }
    *(uint4_t*)base = pkv;
  }
  for (int off = 32; off; off >>= 1) partial += __shfl_xor(partial, off);
  if ((threadIdx.x & 63) == 0 && partial != 0.f) unsafeAtomicAdd(&lsum[p], partial);
}

// ---- GEMM2: O[p][d] += sum_k P[p][k] * Et[d][k]  (split-K atomics) ----
// R2 structure: VGPR staging, single LDS buffer, 2 barriers per BK=64 step.
__global__ __launch_bounds__(256) void k_gemm2(
    const short* __restrict__ P, const short* __restrict__ Et,
    float* __restrict__ O, int c0, int KC, int kseg) {
  __shared__ short lA[128 * 64];
  __shared__ short lB[128 * 64];
  int tid = threadIdx.x, lane = tid & 63;
  int wv = tid >> 6, wr = wv >> 1, wc = wv & 1;
  int rowbase = blockIdx.x * 128;
  int colbase = blockIdx.y * 128;                // output dim (<768)
  int kbase   = blockIdx.z * kseg;               // within chunk
  float4_t acc[4][4];
  float4_t zero = {0.f, 0.f, 0.f, 0.f};
#pragma unroll
  for (int mt = 0; mt < 4; ++mt)
#pragma unroll
    for (int nt = 0; nt < 4; ++nt) acc[mt][nt] = zero;

  for (int kt = 0; kt < kseg / 64; ++kt) {
    __syncthreads();
    stage_vgpr(lA, P,  rowbase, NQ - 1,   KC,   kbase + kt * 64, tid);
    stage_vgpr(lB, Et, colbase, DEMB - 1, VPAD, (long)c0 + kbase + kt * 64, tid);
    __syncthreads();
#pragma unroll
    for (int ks = 0; ks < 2; ++ks) {
      int kb = ks * 64 + (lane >> 4) * 16;
      short8_t a[4], b[4];
#pragma unroll
      for (int mt = 0; mt < 4; ++mt) a[mt] = ldfrag(lA, wr * 64 + mt * 16 + (lane & 15), kb);
#pragma unroll
      for (int nt = 0; nt < 4; ++nt) b[nt] = ldfrag(lB, wc * 64 + nt * 16 + (lane & 15), kb);
#pragma unroll
      for (int mt = 0; mt < 4; ++mt)
#pragma unroll
        for (int nt = 0; nt < 4; ++nt)
          acc[mt][nt] = __builtin_amdgcn_mfma_f32_16x16x32_bf16(a[mt], b[nt], acc[mt][nt], 0, 0, 0);
    }
  }
#pragma unroll
  for (int mt = 0; mt < 4; ++mt)
#pragma unroll
    for (int nt = 0; nt < 4; ++nt) {
      int d = colbase + wc * 64 + nt * 16 + (lane & 15);
#pragma unroll
      for (int r = 0; r < 4; ++r) {
        int p = rowbase + wr * 64 + mt * 16 + ((lane >> 4) << 2) + r;
        unsafeAtomicAdd(&O[(size_t)p * DEMB + d], acc[mt][nt][r]);
      }
    }
}

__global__ void k_finalize(const float* __restrict__ O, const float* __restrict__ lsum,
                           float* __restrict__ out) {
  int idx = blockIdx.x * 256 + threadIdx.x;      // float4 index
  float inv = 1.0f / lsum[idx / 192];            // 192 float4 per row
  float4_t v = ((const float4_t*)O)[idx];
  v[0]*=inv; v[1]*=inv; v[2]*=inv; v[3]*=inv;
  ((float4_t*)out)[idx] = v;
}

// ============================ host launcher ================================
extern "C" void kernel_launch(void* const* d_in, const int* in_sizes, int n_in,
                              void* d_out, int out_size, void* d_ws, size_t ws_size,
                              hipStream_t stream) {
  (void)in_sizes; (void)n_in; (void)out_size;
  const int*   ids = (const int*)d_in[0];
  const float* E   = (const float*)d_in[1];
  float*       out = (float*)d_out;

  char* w = (char*)d_ws;
  short* Eb = (short*)w;      w += (size_t)VPAD * DEMB * 2;   // 77.3 MB
  short* Et = (short*)w;      w += (size_t)DEMB * VPAD * 2;   // 77.3 MB
  short* qn = (short*)w;      w += (size_t)NQ * DEMB * 2;     // 6.3 MB
  float* O  = (float*)w;      w += (size_t)NQ * DEMB * 4;     // 12.6 MB
  float* rk2 = (float*)w;     w += (size_t)VPAD * 4;
  float* lsum = (float*)w;    w += NQ * 4;
  void*  SP = (void*)w;       // f16 sim chunk, overwritten in-place with bf16 P
  size_t fixed = (size_t)(w - (char*)d_ws);

  int KC = 2048;
  if      (fixed + (size_t)NQ * 8192 * 2 <= ws_size) KC = 8192;
  else if (fixed + (size_t)NQ * 4096 * 2 <= ws_size) KC = 4096;
  int chunks = (VPAD + KC - 1) / KC;

  k_zero<<<(NQ * DEMB / 4) / 256, 256, 0, stream>>>(O, lsum);
  k_prep_e<<<VPAD, 256, 0, stream>>>(E, Eb, rk2);
  k_prep_q<<<NQ, 256, 0, stream>>>(ids, E, qn);
  k_transpose<<<dim3(VPAD / 64, DEMB / 32), 256, 0, stream>>>(Eb, Et);

  for (int c = 0; c < chunks; ++c) {
    int c0 = c * KC;
    int KCeff = VPAD - c0; if (KCeff > KC) KCeff = KC;        // multiple of 128
    k_gemm1<<<dim3(NQ / 128, KCeff / 128), 256, 0, stream>>>(qn, Eb, (_Float16*)SP, c0, KC);
    k_gumbel<<<dim3(NQ, (KCeff + 2047) / 2048), 256, 0, stream>>>(
        (uint32_t*)SP, rk2, lsum, c0, KCeff, KC);
    int KS = 4;
    while (KS > 1 && (KCeff % (KS * 64)) != 0) KS >>= 1;
    k_gemm2<<<dim3(NQ / 128, DEMB / 128, KS), 256, 0, stream>>>(
        (const short*)SP, Et, O, c0, KC, KCeff / KS);
  }
  k_finalize<<<(NQ * DEMB / 4) / 256, 256, 0, stream>>>(O, lsum, out);
}